// Round 7
// baseline (812.141 us; speedup 1.0000x reference)
//
#include <hip/hip_runtime.h>
#include <hip/hip_fp16.h>
#include <stdint.h>

// DistMult relational decoder:
//   out[e] = sigmoid( sum_d z[src[e],d] * rel[rel_id[e],d] * z[dst[e],d] )
// N_NODES=100000, E=2000000, D=128, REL_TYPES=64, fp32 in/out.
//
// R7: R2-R6 establish time == L2-miss bytes / ~3.45 TB/s. Attack miss bytes
// with two-level locality: one-pass atomic scatter into 512 buckets
// (src-slice 8 x dst-slice 64). Main kernel: blockIdx&7 -> src-slice (the
// %8->XCD round-robin, whose src-locality effect was measured in R5:
// src misses dropped to ~compulsory), dst-slices walked in increasing order
// so each XCD's L2 holds src slice (3.2 MB, pinned) + active dst slice
// (0.4 MB, streams once). Miss floor ~= 16 (binned) + 26 (src) + 188 (dst)
// ~= 230 MB vs R6's 434 MB. rel fp16 in LDS (R6 win). Scattered out[eid]
// writes accepted (~41 MB, measured R5).

#define NSRC 8
#define NDST 64
#define NBKT 512   // NSRC * NDST

// ---- fp32 -> fp16 converter (8 elems / thread), used for z and rel ----
__global__ __launch_bounds__(256) void convert_kernel(
    const float* __restrict__ x, __half* __restrict__ xh, int n8)
{
    const int i = blockIdx.x * blockDim.x + threadIdx.x;
    if (i >= n8) return;
    const float4 f0 = ((const float4*)x)[2 * i];
    const float4 f1 = ((const float4*)x)[2 * i + 1];
    union { __half2 h2[4]; uint4 u; } o;
    o.h2[0] = __floats2half2_rn(f0.x, f0.y);
    o.h2[1] = __floats2half2_rn(f0.z, f0.w);
    o.h2[2] = __floats2half2_rn(f1.x, f1.y);
    o.h2[3] = __floats2half2_rn(f1.z, f1.w);
    ((uint4*)xh)[i] = o.u;
}

// ---- one-pass bucketing: 512 fixed-capacity regions, global atomics ----
// Within-bucket order is nondeterministic; output is order-invariant
// (each out[eid] written exactly once with an order-independent value).
__global__ __launch_bounds__(256) void scatter512_kernel(
    const int* __restrict__ src, const int* __restrict__ dst,
    const int* __restrict__ relid, int E, int nn, int cap,
    uint32_t* __restrict__ counters, uint64_t* __restrict__ binned)
{
    const int i = blockIdx.x * 256 + threadIdx.x;
    if (i >= E) return;
    const uint32_t s = (uint32_t)src[i];
    const uint32_t d = (uint32_t)dst[i];
    const uint32_t r = (uint32_t)relid[i];
    uint32_t ss = (s * (uint32_t)NSRC) / (uint32_t)nn; if (ss > NSRC - 1) ss = NSRC - 1;
    uint32_t ds = (d * (uint32_t)NDST) / (uint32_t)nn; if (ds > NDST - 1) ds = NDST - 1;
    const uint32_t b = ss * NDST + ds;
    const uint32_t pos = atomicAdd(&counters[b], 1u);
    if (pos < (uint32_t)cap)
        binned[(size_t)b * (size_t)cap + pos] =
            (uint64_t)s | ((uint64_t)d << 17) | ((uint64_t)r << 34) | ((uint64_t)i << 40);
}

// ---- main: bucket (k=blockIdx&7, j walked in order), 2 edges / 16 lanes ----
__global__ __launch_bounds__(256) void distmult_bucketed_kernel(
    const __half* __restrict__ zh,
    const uint64_t* __restrict__ binned,
    const uint32_t* __restrict__ counters,
    const __half* __restrict__ relh,   // [64*128] fp16
    float* __restrict__ out,
    int cap, int cpb)                  // cpb = blocks per bucket
{
    const int k     = blockIdx.x & 7;          // src-slice == XCD affinity
    const int t     = blockIdx.x >> 3;
    const int j     = t / cpb;                 // dst-slice, increases with time
    const int chunk = t - j * cpb;
    const int bkt   = k * NDST + j;

    uint32_t cnt = counters[bkt];
    if (cnt > (uint32_t)cap) cnt = (uint32_t)cap;
    const uint32_t el_blk = (uint32_t)chunk * 32u;
    if (el_blk >= cnt) return;                 // block-uniform early exit

    __shared__ uint4 rel_lds[1024];            // 64 rows * 16 uint4 = 16 KB
    {
        const uint4* rsrc = (const uint4*)relh;
        #pragma unroll
        for (int q = 0; q < 4; q++)
            rel_lds[threadIdx.x + 256 * q] = rsrc[threadIdx.x + 256 * q];
    }
    __syncthreads();

    const int g    = threadIdx.x >> 4;
    const int lane = threadIdx.x & 15;
    const uint32_t el0 = el_blk + (uint32_t)g * 2u;
    if (el0 >= cnt) return;
    const bool has1 = (el0 + 1u < cnt);

    const uint64_t* bb = binned + (size_t)bkt * (size_t)cap;
    const uint64_t p0 = bb[el0];
    const uint64_t p1 = has1 ? bb[el0 + 1u] : p0;

    const uint32_t s0 = (uint32_t)p0 & 0x1FFFFu;
    const uint32_t d0 = (uint32_t)(p0 >> 17) & 0x1FFFFu;
    const uint32_t r0 = (uint32_t)(p0 >> 34) & 0x3Fu;
    const uint32_t e0 = (uint32_t)(p0 >> 40);
    const uint32_t s1 = (uint32_t)p1 & 0x1FFFFu;
    const uint32_t d1 = (uint32_t)(p1 >> 17) & 0x1FFFFu;
    const uint32_t r1 = (uint32_t)(p1 >> 34) & 0x3Fu;
    const uint32_t e1 = (uint32_t)(p1 >> 40);

    // 4 independent global 16 B gathers in flight per lane
    union { uint4 u; __half2 h2[4]; } A0, B0, A1, B1, R0, R1;
    A0.u = ((const uint4*)(zh + (size_t)s0 * 128))[lane];
    B0.u = ((const uint4*)(zh + (size_t)d0 * 128))[lane];
    A1.u = ((const uint4*)(zh + (size_t)s1 * 128))[lane];
    B1.u = ((const uint4*)(zh + (size_t)d1 * 128))[lane];
    R0.u = rel_lds[r0 * 16 + lane];
    R1.u = rel_lds[r1 * 16 + lane];

    float v0 = 0.f, v1 = 0.f;
    #pragma unroll
    for (int q = 0; q < 4; q++) {
        const float2 a0 = __half22float2(A0.h2[q]);
        const float2 b0 = __half22float2(B0.h2[q]);
        const float2 c0 = __half22float2(R0.h2[q]);
        v0 += a0.x * c0.x * b0.x + a0.y * c0.y * b0.y;
        const float2 a1 = __half22float2(A1.h2[q]);
        const float2 b1 = __half22float2(B1.h2[q]);
        const float2 c1 = __half22float2(R1.h2[q]);
        v1 += a1.x * c1.x * b1.x + a1.y * c1.y * b1.y;
    }

    #pragma unroll
    for (int off = 8; off > 0; off >>= 1) {
        v0 += __shfl_down(v0, off, 16);
        v1 += __shfl_down(v1, off, 16);
    }

    if (lane == 0) {
        out[e0] = 1.0f / (1.0f + __expf(-v0));
        if (has1) out[e1] = 1.0f / (1.0f + __expf(-v1));
    }
}

// ---- fallback: R6 kernel (z fp16 gathers, rel fp16 LDS, natural order) ----
__global__ __launch_bounds__(256) void distmult_f16_lds_kernel(
    const __half* __restrict__ zh,
    const int* __restrict__ src_idx, const int* __restrict__ dst_idx,
    const int* __restrict__ rel_id, const __half* __restrict__ relh,
    float* __restrict__ out, int E)
{
    __shared__ uint4 rel_lds[1024];
    {
        const uint4* rsrc = (const uint4*)relh;
        #pragma unroll
        for (int q = 0; q < 4; q++)
            rel_lds[threadIdx.x + 256 * q] = rsrc[threadIdx.x + 256 * q];
    }
    __syncthreads();

    const int gtid = blockIdx.x * blockDim.x + threadIdx.x;
    const int g = gtid >> 4;
    const int lane = threadIdx.x & 15;
    const int e0 = g * 2, e1 = e0 + 1;
    if (e0 >= E) return;
    const bool has1 = (e1 < E);

    const int s0 = src_idx[e0], d0 = dst_idx[e0], r0 = rel_id[e0];
    const int s1 = has1 ? src_idx[e1] : s0;
    const int d1 = has1 ? dst_idx[e1] : d0;
    const int r1 = has1 ? rel_id[e1]  : r0;

    union { uint4 u; __half2 h2[4]; } A0, B0, A1, B1, R0, R1;
    A0.u = ((const uint4*)(zh + (size_t)s0 * 128))[lane];
    B0.u = ((const uint4*)(zh + (size_t)d0 * 128))[lane];
    A1.u = ((const uint4*)(zh + (size_t)s1 * 128))[lane];
    B1.u = ((const uint4*)(zh + (size_t)d1 * 128))[lane];
    R0.u = rel_lds[r0 * 16 + lane];
    R1.u = rel_lds[r1 * 16 + lane];

    float v0 = 0.f, v1 = 0.f;
    #pragma unroll
    for (int q = 0; q < 4; q++) {
        const float2 a0 = __half22float2(A0.h2[q]);
        const float2 b0 = __half22float2(B0.h2[q]);
        const float2 c0 = __half22float2(R0.h2[q]);
        v0 += a0.x * c0.x * b0.x + a0.y * c0.y * b0.y;
        const float2 a1 = __half22float2(A1.h2[q]);
        const float2 b1 = __half22float2(B1.h2[q]);
        const float2 c1 = __half22float2(R1.h2[q]);
        v1 += a1.x * c1.x * b1.x + a1.y * c1.y * b1.y;
    }
    #pragma unroll
    for (int off = 8; off > 0; off >>= 1) {
        v0 += __shfl_down(v0, off, 16);
        v1 += __shfl_down(v1, off, 16);
    }
    if (lane == 0) {
        const float o0 = 1.0f / (1.0f + __expf(-v0));
        if (has1) {
            const float o1 = 1.0f / (1.0f + __expf(-v1));
            *((float2*)(out + e0)) = make_float2(o0, o1);
        } else {
            out[e0] = o0;
        }
    }
}

// ---- fallback: pure fp32 ----
__global__ __launch_bounds__(256) void distmult_f32_kernel(
    const float* __restrict__ z,
    const int* __restrict__ src_idx, const int* __restrict__ dst_idx,
    const int* __restrict__ rel_id, const float* __restrict__ rel,
    float* __restrict__ out, int E)
{
    const int gtid = blockIdx.x * blockDim.x + threadIdx.x;
    const int e = gtid >> 4;
    const int lane = threadIdx.x & 15;
    if (e >= E) return;
    const int s = src_idx[e], d = dst_idx[e], r = rel_id[e];
    const float4* zs = (const float4*)(z + (size_t)s * 128);
    const float4* zd = (const float4*)(z + (size_t)d * 128);
    const float4* rr = (const float4*)(rel + (size_t)r * 128);
    const float4 a0 = zs[lane], a1 = zs[lane + 16];
    const float4 b0 = zd[lane], b1 = zd[lane + 16];
    const float4 c0 = rr[lane], c1 = rr[lane + 16];
    float v = a0.x * c0.x * b0.x + a0.y * c0.y * b0.y
            + a0.z * c0.z * b0.z + a0.w * c0.w * b0.w
            + a1.x * c1.x * b1.x + a1.y * c1.y * b1.y
            + a1.z * c1.z * b1.z + a1.w * c1.w * b1.w;
    #pragma unroll
    for (int off = 8; off > 0; off >>= 1) v += __shfl_down(v, off, 16);
    if (lane == 0) out[e] = 1.0f / (1.0f + __expf(-v));
}

extern "C" void kernel_launch(void* const* d_in, const int* in_sizes, int n_in,
                              void* d_out, int out_size, void* d_ws, size_t ws_size,
                              hipStream_t stream) {
    const float* z     = (const float*)d_in[0];
    const int*   eidx  = (const int*)d_in[1];   // [2, E] flat: src then dst
    const int*   relid = (const int*)d_in[2];
    const float* rel   = (const float*)d_in[3];
    float*       out   = (float*)d_out;

    const int nz   = in_sizes[0];        // N_NODES * 128
    const int E    = in_sizes[2];        // 2,000,000
    const int nrel = in_sizes[3];        // 64 * 128
    const int nn   = nz / 128;           // N_NODES
    const int* src = eidx;
    const int* dst = eidx + E;

    // bucket capacity: mean + ~11 sigma, rounded to 32
    const int mean_b = E / NBKT;
    int cap = mean_b + E / 8192 + 512;
    cap = (cap + 31) & ~31;
    const int cpb = cap / 32;            // blocks per bucket (32 edges/block)

    // ws layout
    const size_t sz_zh    = (size_t)nz * sizeof(__half);
    const size_t off_rh   = (sz_zh + 255) & ~(size_t)255;
    const size_t sz_rh    = (size_t)nrel * sizeof(__half);
    const size_t off_cnt  = (off_rh + sz_rh + 255) & ~(size_t)255;
    const size_t sz_cnt   = (size_t)NBKT * 4;
    const size_t off_bin  = (off_cnt + sz_cnt + 255) & ~(size_t)255;
    const size_t sz_bin   = (size_t)NBKT * (size_t)cap * 8;
    const size_t need     = off_bin + sz_bin;

    const bool rel_ok  = (nrel == 64 * 128);
    const bool bits_ok = (nn <= 131072) && (E <= (1 << 24)) && (nz % 8 == 0);

    if (ws_size >= need && rel_ok && bits_ok) {
        char* ws = (char*)d_ws;
        __half*   zh       = (__half*)(ws);
        __half*   rh       = (__half*)(ws + off_rh);
        uint32_t* counters = (uint32_t*)(ws + off_cnt);
        uint64_t* binned   = (uint64_t*)(ws + off_bin);

        const int n8z = nz / 8, n8r = nrel / 8;
        convert_kernel<<<(n8z + 255) / 256, 256, 0, stream>>>(z, zh, n8z);
        convert_kernel<<<(n8r + 255) / 256, 256, 0, stream>>>(rel, rh, n8r);
        hipMemsetAsync(counters, 0, sz_cnt, stream);
        scatter512_kernel<<<(E + 255) / 256, 256, 0, stream>>>(
            src, dst, relid, E, nn, cap, counters, binned);
        distmult_bucketed_kernel<<<NSRC * NDST * cpb, 256, 0, stream>>>(
            zh, binned, counters, rh, out, cap, cpb);
    } else if (ws_size >= off_rh + sz_rh && rel_ok && nz % 8 == 0) {
        __half* zh = (__half*)d_ws;
        __half* rh = (__half*)((char*)d_ws + off_rh);
        const int n8z = nz / 8, n8r = nrel / 8;
        convert_kernel<<<(n8z + 255) / 256, 256, 0, stream>>>(z, zh, n8z);
        convert_kernel<<<(n8r + 255) / 256, 256, 0, stream>>>(rel, rh, n8r);
        const int groups = (E + 1) / 2;
        const int blocks = (groups * 16 + 255) / 256;
        distmult_f16_lds_kernel<<<blocks, 256, 0, stream>>>(
            zh, src, dst, relid, rh, out, E);
    } else {
        const int blocks = (E * 16 + 255) / 256;
        distmult_f32_kernel<<<blocks, 256, 0, stream>>>(z, src, dst, relid, rel, out, E);
    }
}

// Round 8
// 265.139 us; speedup vs baseline: 3.0631x; 3.0631x over previous
//
#include <hip/hip_runtime.h>
#include <hip/hip_fp16.h>
#include <stdint.h>

// DistMult relational decoder:
//   out[e] = sigmoid( sum_d z[src[e],d] * rel[rel_id[e],d] * z[dst[e],d] )
// N_NODES=100000, E=2000000, D=128, REL_TYPES=64, fp32 in/out.
//
// R8: R7's two-level (src x dst) bucketing main kernel ran ~115 us (vs R6
// 129.5) but the naive scatter (2M global atomics on 512 hot counters,
// VALUBusy 0.46%) cost 598 us. Fix per Guideline 12: per-block LDS
// histogram -> ONE global atomic per (block,bucket) on line-padded
// counters -> LDS-cursor scatter of a contiguous chunk (bucket runs land
// contiguously -> coalesced writes, kills R7's 93 MB RMW amplification).
// Main kernel unchanged: blockIdx&7 -> src-slice (XCD affinity, R5-
// validated), dst-slice walked in block order, rel fp16 in LDS.

#define NSRC 8
#define NDST 64
#define NBKT 512        // NSRC * NDST
#define CNT_STRIDE 16   // one counter per 64 B line
#define SC_BLOCKS 512

// ---- fp32 -> fp16 converter (8 elems / thread), used for z and rel ----
__global__ __launch_bounds__(256) void convert_kernel(
    const float* __restrict__ x, __half* __restrict__ xh, int n8)
{
    const int i = blockIdx.x * blockDim.x + threadIdx.x;
    if (i >= n8) return;
    const float4 f0 = ((const float4*)x)[2 * i];
    const float4 f1 = ((const float4*)x)[2 * i + 1];
    union { __half2 h2[4]; uint4 u; } o;
    o.h2[0] = __floats2half2_rn(f0.x, f0.y);
    o.h2[1] = __floats2half2_rn(f0.z, f0.w);
    o.h2[2] = __floats2half2_rn(f1.x, f1.y);
    o.h2[3] = __floats2half2_rn(f1.z, f1.w);
    ((uint4*)xh)[i] = o.u;
}

__device__ __forceinline__ uint32_t bucket_of2(uint32_t s, uint32_t d, uint32_t nn) {
    uint32_t ss = (s * (uint32_t)NSRC) / nn; if (ss > NSRC - 1) ss = NSRC - 1;
    uint32_t ds = (d * (uint32_t)NDST) / nn; if (ds > NDST - 1) ds = NDST - 1;
    return ss * NDST + ds;
}

// ---- LDS-aggregated bucketing scatter ----
// Phase A: LDS histogram of this block's contiguous chunk.
// Phase B: one global atomicAdd per nonempty bucket (line-padded counters).
// Phase C: re-read chunk, scatter via LDS cursors (contiguous runs/bucket).
// Within-bucket order nondeterministic; output order-invariant (each
// out[eid] written exactly once with an order-independent value).
__global__ __launch_bounds__(256) void scatter_agg_kernel(
    const int* __restrict__ src, const int* __restrict__ dst,
    const int* __restrict__ relid, int E, int nn, int cap,
    uint32_t* __restrict__ counters, uint64_t* __restrict__ binned)
{
    __shared__ uint32_t hist[NBKT];
    __shared__ uint32_t cursor[NBKT];

    const int chunk = (E + (int)gridDim.x - 1) / (int)gridDim.x;
    const int lo = blockIdx.x * chunk;
    const int hi = (lo + chunk < E) ? lo + chunk : E;

    for (int t = threadIdx.x; t < NBKT; t += 256) hist[t] = 0;
    __syncthreads();

    for (int i = lo + (int)threadIdx.x; i < hi; i += 256) {
        const uint32_t b = bucket_of2((uint32_t)src[i], (uint32_t)dst[i], (uint32_t)nn);
        atomicAdd(&hist[b], 1u);
    }
    __syncthreads();

    for (int t = threadIdx.x; t < NBKT; t += 256) {
        const uint32_t c = hist[t];
        cursor[t] = c ? atomicAdd(&counters[t * CNT_STRIDE], c) : 0u;
    }
    __syncthreads();

    for (int i = lo + (int)threadIdx.x; i < hi; i += 256) {
        const uint32_t s = (uint32_t)src[i];
        const uint32_t d = (uint32_t)dst[i];
        const uint32_t r = (uint32_t)relid[i];
        const uint32_t b = bucket_of2(s, d, (uint32_t)nn);
        const uint32_t pos = atomicAdd(&cursor[b], 1u);   // LDS atomic
        if (pos < (uint32_t)cap)
            binned[(size_t)b * (size_t)cap + pos] =
                (uint64_t)s | ((uint64_t)d << 17) | ((uint64_t)r << 34) | ((uint64_t)i << 40);
    }
}

// ---- main: bucket (k=blockIdx&7, j walked in order), 2 edges / 16 lanes ----
__global__ __launch_bounds__(256) void distmult_bucketed_kernel(
    const __half* __restrict__ zh,
    const uint64_t* __restrict__ binned,
    const uint32_t* __restrict__ counters,
    const __half* __restrict__ relh,   // [64*128] fp16
    float* __restrict__ out,
    int cap, int cpb)                  // cpb = blocks per bucket
{
    const int k     = blockIdx.x & 7;          // src-slice == XCD affinity
    const int t     = blockIdx.x >> 3;
    const int j     = t / cpb;                 // dst-slice, increases with time
    const int chunk = t - j * cpb;
    const int bkt   = k * NDST + j;

    uint32_t cnt = counters[bkt * CNT_STRIDE];
    if (cnt > (uint32_t)cap) cnt = (uint32_t)cap;
    const uint32_t el_blk = (uint32_t)chunk * 32u;
    if (el_blk >= cnt) return;                 // block-uniform early exit

    __shared__ uint4 rel_lds[1024];            // 64 rows * 16 uint4 = 16 KB
    {
        const uint4* rsrc = (const uint4*)relh;
        #pragma unroll
        for (int q = 0; q < 4; q++)
            rel_lds[threadIdx.x + 256 * q] = rsrc[threadIdx.x + 256 * q];
    }
    __syncthreads();

    const int g    = threadIdx.x >> 4;
    const int lane = threadIdx.x & 15;
    const uint32_t el0 = el_blk + (uint32_t)g * 2u;
    if (el0 >= cnt) return;
    const bool has1 = (el0 + 1u < cnt);

    const uint64_t* bb = binned + (size_t)bkt * (size_t)cap;
    const uint64_t p0 = bb[el0];
    const uint64_t p1 = has1 ? bb[el0 + 1u] : p0;

    const uint32_t s0 = (uint32_t)p0 & 0x1FFFFu;
    const uint32_t d0 = (uint32_t)(p0 >> 17) & 0x1FFFFu;
    const uint32_t r0 = (uint32_t)(p0 >> 34) & 0x3Fu;
    const uint32_t e0 = (uint32_t)(p0 >> 40);
    const uint32_t s1 = (uint32_t)p1 & 0x1FFFFu;
    const uint32_t d1 = (uint32_t)(p1 >> 17) & 0x1FFFFu;
    const uint32_t r1 = (uint32_t)(p1 >> 34) & 0x3Fu;
    const uint32_t e1 = (uint32_t)(p1 >> 40);

    // 4 independent global 16 B gathers in flight per lane
    union { uint4 u; __half2 h2[4]; } A0, B0, A1, B1, R0, R1;
    A0.u = ((const uint4*)(zh + (size_t)s0 * 128))[lane];
    B0.u = ((const uint4*)(zh + (size_t)d0 * 128))[lane];
    A1.u = ((const uint4*)(zh + (size_t)s1 * 128))[lane];
    B1.u = ((const uint4*)(zh + (size_t)d1 * 128))[lane];
    R0.u = rel_lds[r0 * 16 + lane];
    R1.u = rel_lds[r1 * 16 + lane];

    float v0 = 0.f, v1 = 0.f;
    #pragma unroll
    for (int q = 0; q < 4; q++) {
        const float2 a0 = __half22float2(A0.h2[q]);
        const float2 b0 = __half22float2(B0.h2[q]);
        const float2 c0 = __half22float2(R0.h2[q]);
        v0 += a0.x * c0.x * b0.x + a0.y * c0.y * b0.y;
        const float2 a1 = __half22float2(A1.h2[q]);
        const float2 b1 = __half22float2(B1.h2[q]);
        const float2 c1 = __half22float2(R1.h2[q]);
        v1 += a1.x * c1.x * b1.x + a1.y * c1.y * b1.y;
    }

    #pragma unroll
    for (int off = 8; off > 0; off >>= 1) {
        v0 += __shfl_down(v0, off, 16);
        v1 += __shfl_down(v1, off, 16);
    }

    if (lane == 0) {
        out[e0] = 1.0f / (1.0f + __expf(-v0));
        if (has1) out[e1] = 1.0f / (1.0f + __expf(-v1));
    }
}

// ---- fallback: R6 kernel (z fp16 gathers, rel fp16 LDS, natural order) ----
__global__ __launch_bounds__(256) void distmult_f16_lds_kernel(
    const __half* __restrict__ zh,
    const int* __restrict__ src_idx, const int* __restrict__ dst_idx,
    const int* __restrict__ rel_id, const __half* __restrict__ relh,
    float* __restrict__ out, int E)
{
    __shared__ uint4 rel_lds[1024];
    {
        const uint4* rsrc = (const uint4*)relh;
        #pragma unroll
        for (int q = 0; q < 4; q++)
            rel_lds[threadIdx.x + 256 * q] = rsrc[threadIdx.x + 256 * q];
    }
    __syncthreads();

    const int gtid = blockIdx.x * blockDim.x + threadIdx.x;
    const int g = gtid >> 4;
    const int lane = threadIdx.x & 15;
    const int e0 = g * 2, e1 = e0 + 1;
    if (e0 >= E) return;
    const bool has1 = (e1 < E);

    const int s0 = src_idx[e0], d0 = dst_idx[e0], r0 = rel_id[e0];
    const int s1 = has1 ? src_idx[e1] : s0;
    const int d1 = has1 ? dst_idx[e1] : d0;
    const int r1 = has1 ? rel_id[e1]  : r0;

    union { uint4 u; __half2 h2[4]; } A0, B0, A1, B1, R0, R1;
    A0.u = ((const uint4*)(zh + (size_t)s0 * 128))[lane];
    B0.u = ((const uint4*)(zh + (size_t)d0 * 128))[lane];
    A1.u = ((const uint4*)(zh + (size_t)s1 * 128))[lane];
    B1.u = ((const uint4*)(zh + (size_t)d1 * 128))[lane];
    R0.u = rel_lds[r0 * 16 + lane];
    R1.u = rel_lds[r1 * 16 + lane];

    float v0 = 0.f, v1 = 0.f;
    #pragma unroll
    for (int q = 0; q < 4; q++) {
        const float2 a0 = __half22float2(A0.h2[q]);
        const float2 b0 = __half22float2(B0.h2[q]);
        const float2 c0 = __half22float2(R0.h2[q]);
        v0 += a0.x * c0.x * b0.x + a0.y * c0.y * b0.y;
        const float2 a1 = __half22float2(A1.h2[q]);
        const float2 b1 = __half22float2(B1.h2[q]);
        const float2 c1 = __half22float2(R1.h2[q]);
        v1 += a1.x * c1.x * b1.x + a1.y * c1.y * b1.y;
    }
    #pragma unroll
    for (int off = 8; off > 0; off >>= 1) {
        v0 += __shfl_down(v0, off, 16);
        v1 += __shfl_down(v1, off, 16);
    }
    if (lane == 0) {
        const float o0 = 1.0f / (1.0f + __expf(-v0));
        if (has1) {
            const float o1 = 1.0f / (1.0f + __expf(-v1));
            *((float2*)(out + e0)) = make_float2(o0, o1);
        } else {
            out[e0] = o0;
        }
    }
}

// ---- fallback: pure fp32 ----
__global__ __launch_bounds__(256) void distmult_f32_kernel(
    const float* __restrict__ z,
    const int* __restrict__ src_idx, const int* __restrict__ dst_idx,
    const int* __restrict__ rel_id, const float* __restrict__ rel,
    float* __restrict__ out, int E)
{
    const int gtid = blockIdx.x * blockDim.x + threadIdx.x;
    const int e = gtid >> 4;
    const int lane = threadIdx.x & 15;
    if (e >= E) return;
    const int s = src_idx[e], d = dst_idx[e], r = rel_id[e];
    const float4* zs = (const float4*)(z + (size_t)s * 128);
    const float4* zd = (const float4*)(z + (size_t)d * 128);
    const float4* rr = (const float4*)(rel + (size_t)r * 128);
    const float4 a0 = zs[lane], a1 = zs[lane + 16];
    const float4 b0 = zd[lane], b1 = zd[lane + 16];
    const float4 c0 = rr[lane], c1 = rr[lane + 16];
    float v = a0.x * c0.x * b0.x + a0.y * c0.y * b0.y
            + a0.z * c0.z * b0.z + a0.w * c0.w * b0.w
            + a1.x * c1.x * b1.x + a1.y * c1.y * b1.y
            + a1.z * c1.z * b1.z + a1.w * c1.w * b1.w;
    #pragma unroll
    for (int off = 8; off > 0; off >>= 1) v += __shfl_down(v, off, 16);
    if (lane == 0) out[e] = 1.0f / (1.0f + __expf(-v));
}

extern "C" void kernel_launch(void* const* d_in, const int* in_sizes, int n_in,
                              void* d_out, int out_size, void* d_ws, size_t ws_size,
                              hipStream_t stream) {
    const float* z     = (const float*)d_in[0];
    const int*   eidx  = (const int*)d_in[1];   // [2, E] flat: src then dst
    const int*   relid = (const int*)d_in[2];
    const float* rel   = (const float*)d_in[3];
    float*       out   = (float*)d_out;

    const int nz   = in_sizes[0];        // N_NODES * 128
    const int E    = in_sizes[2];        // 2,000,000
    const int nrel = in_sizes[3];        // 64 * 128
    const int nn   = nz / 128;           // N_NODES
    const int* src = eidx;
    const int* dst = eidx + E;

    // bucket capacity: mean + ~12 sigma, rounded to 32
    const int mean_b = E / NBKT;
    int cap = mean_b + E / 8192 + 512;
    cap = (cap + 31) & ~31;
    const int cpb = cap / 32;            // blocks per bucket (32 edges/block)

    // ws layout
    const size_t sz_zh    = (size_t)nz * sizeof(__half);
    const size_t off_rh   = (sz_zh + 255) & ~(size_t)255;
    const size_t sz_rh    = (size_t)nrel * sizeof(__half);
    const size_t off_cnt  = (off_rh + sz_rh + 255) & ~(size_t)255;
    const size_t sz_cnt   = (size_t)NBKT * CNT_STRIDE * 4;   // 32 KB
    const size_t off_bin  = (off_cnt + sz_cnt + 255) & ~(size_t)255;
    const size_t sz_bin   = (size_t)NBKT * (size_t)cap * 8;
    const size_t need     = off_bin + sz_bin;

    const bool rel_ok  = (nrel == 64 * 128);
    const bool bits_ok = (nn <= 131072) && (E <= (1 << 21)) && (nz % 8 == 0);

    if (ws_size >= need && rel_ok && bits_ok) {
        char* ws = (char*)d_ws;
        __half*   zh       = (__half*)(ws);
        __half*   rh       = (__half*)(ws + off_rh);
        uint32_t* counters = (uint32_t*)(ws + off_cnt);
        uint64_t* binned   = (uint64_t*)(ws + off_bin);

        const int n8z = nz / 8, n8r = nrel / 8;
        convert_kernel<<<(n8z + 255) / 256, 256, 0, stream>>>(z, zh, n8z);
        convert_kernel<<<(n8r + 255) / 256, 256, 0, stream>>>(rel, rh, n8r);
        hipMemsetAsync(counters, 0, sz_cnt, stream);
        scatter_agg_kernel<<<SC_BLOCKS, 256, 0, stream>>>(
            src, dst, relid, E, nn, cap, counters, binned);
        distmult_bucketed_kernel<<<NSRC * NDST * cpb, 256, 0, stream>>>(
            zh, binned, counters, rh, out, cap, cpb);
    } else if (ws_size >= off_rh + sz_rh && rel_ok && nz % 8 == 0) {
        __half* zh = (__half*)d_ws;
        __half* rh = (__half*)((char*)d_ws + off_rh);
        const int n8z = nz / 8, n8r = nrel / 8;
        convert_kernel<<<(n8z + 255) / 256, 256, 0, stream>>>(z, zh, n8z);
        convert_kernel<<<(n8r + 255) / 256, 256, 0, stream>>>(rel, rh, n8r);
        const int groups = (E + 1) / 2;
        const int blocks = (groups * 16 + 255) / 256;
        distmult_f16_lds_kernel<<<blocks, 256, 0, stream>>>(
            zh, src, dst, relid, rh, out, E);
    } else {
        const int blocks = (E * 16 + 255) / 256;
        distmult_f32_kernel<<<blocks, 256, 0, stream>>>(z, src, dst, relid, rel, out, E);
    }
}

// Round 9
// 231.182 us; speedup vs baseline: 3.5130x; 1.1469x over previous
//
#include <hip/hip_runtime.h>
#include <hip/hip_fp16.h>
#include <stdint.h>

// DistMult relational decoder:
//   out[e] = sigmoid( sum_d z[src[e],d] * rel[rel_id[e],d] * z[dst[e],d] )
// N_NODES=100000, E=2000000, D=128, REL_TYPES=64, fp32 in/out.
//
// R9: R8 proved the (src x dst) bucketing halves L2-miss bytes (FETCH
// 434->199 MB) but main kernel became VALU-bound (VALUBusy 73%) and the
// scatter cost ~52 us. This round keeps the locality structure and cuts
// both: main kernel uses 8 lanes/edge (half the shfl rounds, shared load
// bases) + v_pk_mul_f16 / v_dot2_f32_f16 for the triple-product dot
// (16 VALU ops per lane instead of ~40); scatter holds its 16 edges in
// registers (single coalesced index read, full MLP).

#define NSRC 8
#define NDST 64
#define NBKT 512        // NSRC * NDST
#define CNT_STRIDE 16   // one counter per 64 B line
#define SC_BLOCKS 512
#define PE 16           // edges per scatter thread

#if defined(__has_builtin)
#if __has_builtin(__builtin_amdgcn_fdot2)
#define HAS_FDOT2 1
#endif
#endif

typedef _Float16 hv2 __attribute__((ext_vector_type(2)));

// acc += sum over 2 packed elems of a*r*b (fp16 inputs, fp32 accumulate)
__device__ __forceinline__ float dot3_accum(uint32_t a, uint32_t r, uint32_t b,
                                            float acc)
{
#ifdef HAS_FDOT2
    union { uint32_t u; hv2 v; } A, R, B;
    A.u = a; R.u = r; B.u = b;
    const hv2 t = A.v * R.v;                       // v_pk_mul_f16
    return __builtin_amdgcn_fdot2(t, B.v, acc, false);  // v_dot2_f32_f16
#else
    union { uint32_t u; __half2 h; } A, R, B;
    A.u = a; R.u = r; B.u = b;
    const float2 af = __half22float2(A.h);
    const float2 rf = __half22float2(R.h);
    const float2 bf = __half22float2(B.h);
    acc = fmaf(af.x * rf.x, bf.x, acc);
    acc = fmaf(af.y * rf.y, bf.y, acc);
    return acc;
#endif
}

// ---- fp32 -> fp16 converter (8 elems / thread), used for z and rel ----
__global__ __launch_bounds__(256) void convert_kernel(
    const float* __restrict__ x, __half* __restrict__ xh, int n8)
{
    const int i = blockIdx.x * blockDim.x + threadIdx.x;
    if (i >= n8) return;
    const float4 f0 = ((const float4*)x)[2 * i];
    const float4 f1 = ((const float4*)x)[2 * i + 1];
    union { __half2 h2[4]; uint4 u; } o;
    o.h2[0] = __floats2half2_rn(f0.x, f0.y);
    o.h2[1] = __floats2half2_rn(f0.z, f0.w);
    o.h2[2] = __floats2half2_rn(f1.x, f1.y);
    o.h2[3] = __floats2half2_rn(f1.z, f1.w);
    ((uint4*)xh)[i] = o.u;
}

__device__ __forceinline__ uint32_t bucket_of2(uint32_t s, uint32_t d, uint32_t nn) {
    uint32_t ss = (s * (uint32_t)NSRC) / nn; if (ss > NSRC - 1) ss = NSRC - 1;
    uint32_t ds = (d * (uint32_t)NDST) / nn; if (ds > NDST - 1) ds = NDST - 1;
    return ss * NDST + ds;
}

// ---- LDS-aggregated bucketing scatter, register-held edges ----
// One coalesced read of (src,dst,rel) held in registers; LDS histogram ->
// one global atomic per (block,bucket) on line-padded counters -> LDS-cursor
// scatter. Within-bucket order nondeterministic; output order-invariant.
__global__ __launch_bounds__(256) void scatter_reg_kernel(
    const int* __restrict__ src, const int* __restrict__ dst,
    const int* __restrict__ relid, int E, int nn, int cap,
    uint32_t* __restrict__ counters, uint64_t* __restrict__ binned)
{
    __shared__ uint32_t hist[NBKT];
    __shared__ uint32_t cursor[NBKT];

    const int chunk = (E + (int)gridDim.x - 1) / (int)gridDim.x;
    const int lo = blockIdx.x * chunk;
    const int hi = (lo + chunk < E) ? lo + chunk : E;

    for (int t = threadIdx.x; t < NBKT; t += 256) hist[t] = 0;
    __syncthreads();

    uint64_t pay[PE];
    uint32_t bkt[PE];

    #pragma unroll
    for (int p = 0; p < PE; p++) {
        const int i = lo + p * 256 + (int)threadIdx.x;
        if (i < hi) {
            const uint32_t s = (uint32_t)src[i];
            const uint32_t d = (uint32_t)dst[i];
            const uint32_t r = (uint32_t)relid[i];
            const uint32_t b = bucket_of2(s, d, (uint32_t)nn);
            pay[p] = (uint64_t)s | ((uint64_t)d << 17)
                   | ((uint64_t)r << 34) | ((uint64_t)i << 40);
            bkt[p] = b;
            atomicAdd(&hist[b], 1u);
        } else {
            bkt[p] = 0xFFFFFFFFu;
        }
    }
    __syncthreads();

    for (int t = threadIdx.x; t < NBKT; t += 256) {
        const uint32_t c = hist[t];
        cursor[t] = c ? atomicAdd(&counters[t * CNT_STRIDE], c) : 0u;
    }
    __syncthreads();

    #pragma unroll
    for (int p = 0; p < PE; p++) {
        if (bkt[p] != 0xFFFFFFFFu) {
            const uint32_t pos = atomicAdd(&cursor[bkt[p]], 1u);   // LDS atomic
            if (pos < (uint32_t)cap)
                binned[(size_t)bkt[p] * (size_t)cap + pos] = pay[p];
        }
    }
}

// ---- main: bucket (k=blockIdx&7, j walked in order), 8 lanes / edge ----
__global__ __launch_bounds__(256) void distmult_bucketed8_kernel(
    const __half* __restrict__ zh,
    const uint64_t* __restrict__ binned,
    const uint32_t* __restrict__ counters,
    const __half* __restrict__ relh,   // [64*128] fp16
    float* __restrict__ out,
    int cap, int cpb)                  // cpb = blocks per bucket
{
    const int k     = blockIdx.x & 7;          // src-slice == XCD affinity
    const int t     = blockIdx.x >> 3;
    const int j     = t / cpb;                 // dst-slice, increases with time
    const int chunk = t - j * cpb;
    const int bkt   = k * NDST + j;

    uint32_t cnt = counters[bkt * CNT_STRIDE];
    if (cnt > (uint32_t)cap) cnt = (uint32_t)cap;
    const uint32_t el_blk = (uint32_t)chunk * 32u;
    if (el_blk >= cnt) return;                 // block-uniform early exit

    __shared__ uint4 rel_lds[1024];            // 64 rows * 16 uint4 = 16 KB
    {
        const uint4* rsrc = (const uint4*)relh;
        #pragma unroll
        for (int q = 0; q < 4; q++)
            rel_lds[threadIdx.x + 256 * q] = rsrc[threadIdx.x + 256 * q];
    }
    __syncthreads();

    const int g    = threadIdx.x >> 3;         // 0..31: edge group
    const int lane = threadIdx.x & 7;          // 0..7 within edge
    const uint32_t el = el_blk + (uint32_t)g;
    if (el >= cnt) return;

    const uint64_t p = binned[(size_t)bkt * (size_t)cap + el];
    const uint32_t s   = (uint32_t)p & 0x1FFFFu;
    const uint32_t d   = (uint32_t)(p >> 17) & 0x1FFFFu;
    const uint32_t r   = (uint32_t)(p >> 34) & 0x3Fu;
    const uint32_t eid = (uint32_t)(p >> 40);

    // lane covers elements [lane*16, lane*16+16): two uint4 per row,
    // shared base -> one addr calc + offset immediates.
    union U4 { uint4 q; uint32_t w[4]; };
    const uint4* sb = (const uint4*)(zh + (size_t)s * 128);
    const uint4* db = (const uint4*)(zh + (size_t)d * 128);
    U4 A0, A1, B0, B1, R0, R1;
    A0.q = sb[lane * 2];
    A1.q = sb[lane * 2 + 1];
    B0.q = db[lane * 2];
    B1.q = db[lane * 2 + 1];
    R0.q = rel_lds[r * 16 + lane * 2];
    R1.q = rel_lds[r * 16 + lane * 2 + 1];

    float acc = 0.f;
    #pragma unroll
    for (int q = 0; q < 4; q++) {
        acc = dot3_accum(A0.w[q], R0.w[q], B0.w[q], acc);
        acc = dot3_accum(A1.w[q], R1.w[q], B1.w[q], acc);
    }

    // reduce across the 8 lanes of this edge
    #pragma unroll
    for (int off = 4; off > 0; off >>= 1)
        acc += __shfl_down(acc, off, 8);

    if (lane == 0)
        out[eid] = 1.0f / (1.0f + __expf(-acc));
}

// ---- fallback: R6 kernel (z fp16 gathers, rel fp16 LDS, natural order) ----
__global__ __launch_bounds__(256) void distmult_f16_lds_kernel(
    const __half* __restrict__ zh,
    const int* __restrict__ src_idx, const int* __restrict__ dst_idx,
    const int* __restrict__ rel_id, const __half* __restrict__ relh,
    float* __restrict__ out, int E)
{
    __shared__ uint4 rel_lds[1024];
    {
        const uint4* rsrc = (const uint4*)relh;
        #pragma unroll
        for (int q = 0; q < 4; q++)
            rel_lds[threadIdx.x + 256 * q] = rsrc[threadIdx.x + 256 * q];
    }
    __syncthreads();

    const int gtid = blockIdx.x * blockDim.x + threadIdx.x;
    const int g = gtid >> 4;
    const int lane = threadIdx.x & 15;
    const int e0 = g * 2, e1 = e0 + 1;
    if (e0 >= E) return;
    const bool has1 = (e1 < E);

    const int s0 = src_idx[e0], d0 = dst_idx[e0], r0 = rel_id[e0];
    const int s1 = has1 ? src_idx[e1] : s0;
    const int d1 = has1 ? dst_idx[e1] : d0;
    const int r1 = has1 ? rel_id[e1]  : r0;

    union U4 { uint4 q; uint32_t w[4]; };
    U4 A0, B0, A1, B1, R0, R1;
    A0.q = ((const uint4*)(zh + (size_t)s0 * 128))[lane];
    B0.q = ((const uint4*)(zh + (size_t)d0 * 128))[lane];
    A1.q = ((const uint4*)(zh + (size_t)s1 * 128))[lane];
    B1.q = ((const uint4*)(zh + (size_t)d1 * 128))[lane];
    R0.q = rel_lds[r0 * 16 + lane];
    R1.q = rel_lds[r1 * 16 + lane];

    float v0 = 0.f, v1 = 0.f;
    #pragma unroll
    for (int q = 0; q < 4; q++) {
        v0 = dot3_accum(A0.w[q], R0.w[q], B0.w[q], v0);
        v1 = dot3_accum(A1.w[q], R1.w[q], B1.w[q], v1);
    }
    #pragma unroll
    for (int off = 8; off > 0; off >>= 1) {
        v0 += __shfl_down(v0, off, 16);
        v1 += __shfl_down(v1, off, 16);
    }
    if (lane == 0) {
        const float o0 = 1.0f / (1.0f + __expf(-v0));
        if (has1) {
            const float o1 = 1.0f / (1.0f + __expf(-v1));
            *((float2*)(out + e0)) = make_float2(o0, o1);
        } else {
            out[e0] = o0;
        }
    }
}

// ---- fallback: pure fp32 ----
__global__ __launch_bounds__(256) void distmult_f32_kernel(
    const float* __restrict__ z,
    const int* __restrict__ src_idx, const int* __restrict__ dst_idx,
    const int* __restrict__ rel_id, const float* __restrict__ rel,
    float* __restrict__ out, int E)
{
    const int gtid = blockIdx.x * blockDim.x + threadIdx.x;
    const int e = gtid >> 4;
    const int lane = threadIdx.x & 15;
    if (e >= E) return;
    const int s = src_idx[e], d = dst_idx[e], r = rel_id[e];
    const float4* zs = (const float4*)(z + (size_t)s * 128);
    const float4* zd = (const float4*)(z + (size_t)d * 128);
    const float4* rr = (const float4*)(rel + (size_t)r * 128);
    const float4 a0 = zs[lane], a1 = zs[lane + 16];
    const float4 b0 = zd[lane], b1 = zd[lane + 16];
    const float4 c0 = rr[lane], c1 = rr[lane + 16];
    float v = a0.x * c0.x * b0.x + a0.y * c0.y * b0.y
            + a0.z * c0.z * b0.z + a0.w * c0.w * b0.w
            + a1.x * c1.x * b1.x + a1.y * c1.y * b1.y
            + a1.z * c1.z * b1.z + a1.w * c1.w * b1.w;
    #pragma unroll
    for (int off = 8; off > 0; off >>= 1) v += __shfl_down(v, off, 16);
    if (lane == 0) out[e] = 1.0f / (1.0f + __expf(-v));
}

extern "C" void kernel_launch(void* const* d_in, const int* in_sizes, int n_in,
                              void* d_out, int out_size, void* d_ws, size_t ws_size,
                              hipStream_t stream) {
    const float* z     = (const float*)d_in[0];
    const int*   eidx  = (const int*)d_in[1];   // [2, E] flat: src then dst
    const int*   relid = (const int*)d_in[2];
    const float* rel   = (const float*)d_in[3];
    float*       out   = (float*)d_out;

    const int nz   = in_sizes[0];        // N_NODES * 128
    const int E    = in_sizes[2];        // 2,000,000
    const int nrel = in_sizes[3];        // 64 * 128
    const int nn   = nz / 128;           // N_NODES
    const int* src = eidx;
    const int* dst = eidx + E;

    // bucket capacity: mean + ~12 sigma, rounded to 32
    const int mean_b = E / NBKT;
    int cap = mean_b + E / 8192 + 512;
    cap = (cap + 31) & ~31;
    const int cpb = cap / 32;            // blocks per bucket (32 edges/block)

    // scatter must cover E with PE edges/thread
    const int sc_blocks = ((E + PE * 256 - 1) / (PE * 256) > SC_BLOCKS)
                        ? (E + PE * 256 - 1) / (PE * 256) : SC_BLOCKS;

    // ws layout
    const size_t sz_zh    = (size_t)nz * sizeof(__half);
    const size_t off_rh   = (sz_zh + 255) & ~(size_t)255;
    const size_t sz_rh    = (size_t)nrel * sizeof(__half);
    const size_t off_cnt  = (off_rh + sz_rh + 255) & ~(size_t)255;
    const size_t sz_cnt   = (size_t)NBKT * CNT_STRIDE * 4;   // 32 KB
    const size_t off_bin  = (off_cnt + sz_cnt + 255) & ~(size_t)255;
    const size_t sz_bin   = (size_t)NBKT * (size_t)cap * 8;
    const size_t need     = off_bin + sz_bin;

    const bool rel_ok  = (nrel == 64 * 128);
    const bool bits_ok = (nn <= 131072) && (E <= (1 << 21)) && (nz % 8 == 0);

    if (ws_size >= need && rel_ok && bits_ok) {
        char* ws = (char*)d_ws;
        __half*   zh       = (__half*)(ws);
        __half*   rh       = (__half*)(ws + off_rh);
        uint32_t* counters = (uint32_t*)(ws + off_cnt);
        uint64_t* binned   = (uint64_t*)(ws + off_bin);

        const int n8z = nz / 8, n8r = nrel / 8;
        convert_kernel<<<(n8z + 255) / 256, 256, 0, stream>>>(z, zh, n8z);
        convert_kernel<<<(n8r + 255) / 256, 256, 0, stream>>>(rel, rh, n8r);
        hipMemsetAsync(counters, 0, sz_cnt, stream);
        scatter_reg_kernel<<<sc_blocks, 256, 0, stream>>>(
            src, dst, relid, E, nn, cap, counters, binned);
        distmult_bucketed8_kernel<<<NSRC * NDST * cpb, 256, 0, stream>>>(
            zh, binned, counters, rh, out, cap, cpb);
    } else if (ws_size >= off_rh + sz_rh && rel_ok && nz % 8 == 0) {
        __half* zh = (__half*)d_ws;
        __half* rh = (__half*)((char*)d_ws + off_rh);
        const int n8z = nz / 8, n8r = nrel / 8;
        convert_kernel<<<(n8z + 255) / 256, 256, 0, stream>>>(z, zh, n8z);
        convert_kernel<<<(n8r + 255) / 256, 256, 0, stream>>>(rel, rh, n8r);
        const int groups = (E + 1) / 2;
        const int blocks = (groups * 16 + 255) / 256;
        distmult_f16_lds_kernel<<<blocks, 256, 0, stream>>>(
            zh, src, dst, relid, rh, out, E);
    } else {
        const int blocks = (E * 16 + 255) / 256;
        distmult_f32_kernel<<<blocks, 256, 0, stream>>>(z, src, dst, relid, rel, out, E);
    }
}